// Round 5
// baseline (420.185 us; speedup 1.0000x reference)
//
#include <hip/hip_runtime.h>
#include <climits>
#include <cmath>

// DetectPeaks: xcorr [16,1,256,8192] f32 -> (neighbor_score, topk_scores, topk_index), each [rows,3]
// rows = 4096, W = 8192.
// Round-5 structure: persistent-ish kernel. 512 blocks x 1024 threads (16 waves) = exactly
// 2 blocks/CU, each block handles 8 rows. Software-pipelined across rows: next row's loads
// (2 dwordx4/thread) are issued BEFORE the current row's merge; the merge barrier pins them
// early, so ~64 KB/CU stays in flight continuously (copy-kernel-like duty cycle).
// Per row: wave w owns elements [w*512,(w+1)*512); neighbors via shfl; quad top-2 pruning;
// shfl-tree wave merge; 48 partials -> wave 0 parallel shfl-tree; lanes 0-2 write the tail.

#define PW     8192
#define PNLAG  (PW / 2)
#define TPB    1024
#define NWAVES 16            // waves per block
#define GRID   512           // 2 blocks/CU exactly; 4096/512 = 8 rows per block

__device__ __forceinline__ bool better(float av, int ai, float bv, int bi) {
  return (av > bv) || ((av == bv) && (ai < bi));   // lax.top_k: ties -> lower index
}

__device__ __forceinline__ void insert3_full(float v, int i,
                                             float &v0, int &i0,
                                             float &v1, int &i1,
                                             float &v2, int &i2) {
  if (better(v, i, v2, i2)) {
    if (better(v, i, v1, i1)) {
      if (better(v, i, v0, i0)) {
        v2 = v1; i2 = i1; v1 = v0; i1 = i0; v0 = v; i0 = i;
      } else {
        v2 = v1; i2 = i1; v1 = v; i1 = i;
      }
    } else {
      v2 = v; i2 = i;
    }
  }
}

// Exact float ties between distinct lags have ~0 probability; strict > suffices.
__device__ __forceinline__ void insert3_fast(float c, int ci,
                                             float &v0, int &i0,
                                             float &v1, int &i1,
                                             float &v2, int &i2) {
  const bool b2 = c > v2;
  const bool b1 = c > v1;
  const bool b0 = c > v0;
  v2 = b1 ? v1 : (b2 ? c : v2);  i2 = b1 ? i1 : (b2 ? ci : i2);
  v1 = b0 ? v0 : (b1 ? c : v1);  i1 = b0 ? i0 : (b1 ? ci : i1);
  v0 = b0 ? c  : v0;             i0 = b0 ? ci : i0;
}

// NMS + quad top-2 for 4 contiguous elems starting at p, with outside neighbors l/r.
__device__ __forceinline__ void quad_cands(const float4 v, float left, float right, int p,
                                           float &v0, int &i0, float &v1, int &i1,
                                           float &v2, int &i2) {
  const float p01 = fmaxf(v.x, v.y);
  const float p12 = fmaxf(v.y, v.z);
  const float p23 = fmaxf(v.z, v.w);
  const float m0 = fmaxf(left, p01);
  const float m1 = fmaxf(p01, v.z);
  const float m2 = fmaxf(p12, v.w);
  const float m3 = fmaxf(p23, right);
  const float s0 = (v.x == m0) ? v.x : 0.0f;
  const float s1 = (v.y == m1) ? v.y : 0.0f;
  const float s2 = (v.z == m2) ? v.z : 0.0f;
  const float s3 = (v.w == m3) ? v.w : 0.0f;
  // a window of 4 contiguous lags holds at most 2 local maxima;
  // left arg of >= always has lower index => tie -> lower index preserved.
  const bool  a01 = s0 >= s1;
  const float hiA = a01 ? s0 : s1;   const int hiAi = a01 ? p     : p + 1;
  const float loA = a01 ? s1 : s0;   const int loAi = a01 ? p + 1 : p;
  const bool  a23 = s2 >= s3;
  const float hiB = a23 ? s2 : s3;   const int hiBi = a23 ? p + 2 : p + 3;
  const float loB = a23 ? s3 : s2;   const int loBi = a23 ? p + 3 : p + 2;
  const bool  ab  = hiA >= hiB;
  const float c1  = ab ? hiA : hiB;  const int c1i = ab ? hiAi : hiBi;
  const bool  sb  = ab ? (loA >= hiB) : (hiA >= loB);
  const float c2  = ab ? (sb ? loA : hiB) : (sb ? hiA : loB);
  const int   c2i = ab ? (sb ? loAi : hiBi) : (sb ? hiAi : loBi);
  insert3_fast(c1, c1i, v0, i0, v1, i1, v2, i2);
  insert3_fast(c2, c2i, v0, i0, v1, i1, v2, i2);
}

__global__ __launch_bounds__(TPB)
void detect_peaks_kernel(const float* __restrict__ x,
                         float* __restrict__ out,
                         int rows) {
  __shared__ float sv[2][NWAVES][3];   // double-buffered per-wave partials
  __shared__ int   si[2][NWAVES][3];

  const int t     = threadIdx.x;
  const int lane  = t & 63;
  const int wave  = t >> 6;
  const int qAidx = wave * 128 + lane;     // quad index of first quad
  const int qBidx = qAidx + 64;            // second quad
  const int spanL = wave * 512;            // first element of this wave's span

  float* __restrict__ nb = out;                      // neighbor_score
  float* __restrict__ ts = out + (size_t)rows * 3;   // topk_scores
  float* __restrict__ ti = out + (size_t)rows * 6;   // topk_index (as float)

  int row = blockIdx.x;

  // ---- preamble: loads for first row ----
  const float* xr0 = x + (size_t)row * PW;
  float4 qA = ((const float4*)xr0)[qAidx];
  float4 qB = ((const float4*)xr0)[qBidx];
  float  eL = (lane == 0  && wave > 0)          ? xr0[spanL - 1]   : -INFINITY;
  float  eR = (lane == 63 && wave < NWAVES - 1) ? xr0[spanL + 512] : -INFINITY;

  int pb = 0;
  while (row < rows) {
    const float* __restrict__ xr_cur = x + (size_t)row * PW;
    const int nrow = row + GRID;

    // ---- issue NEXT row's loads first (independent of current-row consumption) ----
    float4 qA2 = {0, 0, 0, 0}, qB2 = {0, 0, 0, 0};
    float  eL2 = -INFINITY, eR2 = -INFINITY;
    if (nrow < rows) {
      const float* __restrict__ xn = x + (size_t)nrow * PW;
      qA2 = ((const float4*)xn)[qAidx];
      qB2 = ((const float4*)xn)[qBidx];
      if (lane == 0  && wave > 0)          eL2 = xn[spanL - 1];
      if (lane == 63 && wave < NWAVES - 1) eR2 = xn[spanL + 512];
    }

    // ---- consume current row: neighbors via shfl, quad top-2 -> register top-3 ----
    const float luA = __shfl_up(qA.w, 1);
    const float rdA = __shfl_down(qA.x, 1);
    const float bxB = __shfl(qB.x, 0);      // right neighbor of lane63's qA.w
    const float luB = __shfl_up(qB.w, 1);
    const float rdB = __shfl_down(qB.x, 1);
    const float awB = __shfl(qA.w, 63);     // left neighbor of lane0's qB.x

    const float lA = (lane == 0)  ? eL  : luA;
    const float rA = (lane == 63) ? bxB : rdA;
    const float lB = (lane == 0)  ? awB : luB;
    const float rB = (lane == 63) ? eR  : rdB;

    float v0 = -INFINITY, v1 = -INFINITY, v2 = -INFINITY;
    int   i0 = INT_MAX,   i1 = INT_MAX,   i2 = INT_MAX;
    quad_cands(qA, lA, rA, qAidx * 4, v0, i0, v1, i1, v2, i2);
    quad_cands(qB, lB, rB, qBidx * 4, v0, i0, v1, i1, v2, i2);

    // ---- wave-level shfl-tree merge ----
#pragma unroll
    for (int off = 32; off > 0; off >>= 1) {
      float ov0 = __shfl_down(v0, off);
      int   oi0 = __shfl_down(i0, off);
      float ov1 = __shfl_down(v1, off);
      int   oi1 = __shfl_down(i1, off);
      float ov2 = __shfl_down(v2, off);
      int   oi2 = __shfl_down(i2, off);
      if (lane + off < 64) {
        insert3_full(ov0, oi0, v0, i0, v1, i1, v2, i2);
        insert3_full(ov1, oi1, v0, i0, v1, i1, v2, i2);
        insert3_full(ov2, oi2, v0, i0, v1, i1, v2, i2);
      }
    }
    if (lane == 0) {
      sv[pb][wave][0] = v0; si[pb][wave][0] = i0;
      sv[pb][wave][1] = v1; si[pb][wave][1] = i1;
      sv[pb][wave][2] = v2; si[pb][wave][2] = i2;
    }
    __syncthreads();   // also pins the next-row loads before this point

    // ---- wave 0: parallel merge of 48 partials + output tail ----
    if (wave == 0) {
      float mv = -INFINITY; int mi = INT_MAX;
      if (lane < NWAVES * 3) {
        mv = sv[pb][lane / 3][lane % 3];
        mi = si[pb][lane / 3][lane % 3];
      }
      float w0 = mv,       w1 = -INFINITY, w2 = -INFINITY;
      int   j0 = mi,       j1 = INT_MAX,   j2 = INT_MAX;
#pragma unroll
      for (int off = 32; off > 0; off >>= 1) {
        float o0 = __shfl_down(w0, off);
        int   k0 = __shfl_down(j0, off);
        float o1 = __shfl_down(w1, off);
        int   k1 = __shfl_down(j1, off);
        float o2 = __shfl_down(w2, off);
        int   k2 = __shfl_down(j2, off);
        if (lane + off < 64) {
          insert3_full(o0, k0, w0, j0, w1, j1, w2, j2);
          insert3_full(o1, k1, w0, j0, w1, j1, w2, j2);
          insert3_full(o2, k2, w0, j0, w1, j1, w2, j2);
        }
      }
      // broadcast lane0's top-3, write tail with lanes 0..2
      const float b0 = __shfl(w0, 0);  const int c0 = __shfl(j0, 0);
      const float b1 = __shfl(w1, 0);  const int c1 = __shfl(j1, 0);
      const float b2 = __shfl(w2, 0);  const int c2 = __shfl(j2, 0);
      if (lane < 3) {
        int idx = c0 - 1 + lane;
        idx = idx < 0 ? 0 : (idx > PW - 1 ? PW - 1 : idx);
        nb[row * 3 + lane] = xr_cur[idx];                       // L2-warm gather
        ts[row * 3 + lane] = (lane == 0) ? b0 : (lane == 1) ? b1 : b2;
        const int tix      = (lane == 0) ? c0 : (lane == 1) ? c1 : c2;
        ti[row * 3 + lane] = (float)(tix - PNLAG);
      }
    }

    // ---- rotate pipeline ----
    qA = qA2; qB = qB2; eL = eL2; eR = eR2;
    row = nrow;
    pb ^= 1;
  }
}

extern "C" void kernel_launch(void* const* d_in, const int* in_sizes, int n_in,
                              void* d_out, int out_size, void* d_ws, size_t ws_size,
                              hipStream_t stream) {
  const float* x = (const float*)d_in[0];
  float* out = (float*)d_out;
  const int rows = in_sizes[0] / PW;   // 4096
  detect_peaks_kernel<<<GRID, TPB, 0, stream>>>(x, out, rows);
}

// Round 8
// 239.394 us; speedup vs baseline: 1.7552x; 1.7552x over previous
//
#include <hip/hip_runtime.h>
#include <climits>
#include <cmath>

// DetectPeaks: xcorr [16,1,256,8192] f32 -> (neighbor_score, topk_scores, topk_index), each [rows,3]
// rows = 4096, W = 8192. One block (4 waves) per row, wave w owns elements [w*2048,(w+1)*2048).
// Round-8: ALL loads + s_waitcnt vmcnt(0) inside ONE asm block (earlyclobber outputs).
// Guarantees 8x dwordx4 + 2x dword outstanding per thread (8.25 KB/wave in flight) and is
// correctness-sound: asm outputs only become live after the in-block drain, so the register
// allocator can never copy an unlanded VMEM dest (the R7 failure mode).
// Compute/merge identical to R3 (absmax 0 verified).

#define PW    8192
#define PNLAG (PW / 2)
#define BLOCK 256
#define NW    4
#define J     8                 // quads per thread; wave span = J*64 quads = 2048 elems

__device__ __forceinline__ bool better(float av, int ai, float bv, int bi) {
  return (av > bv) || ((av == bv) && (ai < bi));   // lax.top_k: ties -> lower index
}

__device__ __forceinline__ void insert3_full(float v, int i,
                                             float &v0, int &i0,
                                             float &v1, int &i1,
                                             float &v2, int &i2) {
  if (better(v, i, v2, i2)) {
    if (better(v, i, v1, i1)) {
      if (better(v, i, v0, i0)) {
        v2 = v1; i2 = i1; v1 = v0; i1 = i0; v0 = v; i0 = i;
      } else {
        v2 = v1; i2 = i1; v1 = v; i1 = i;
      }
    } else {
      v2 = v; i2 = i;
    }
  }
}

// Exact float ties between distinct lags have ~0 probability; strict > suffices.
__device__ __forceinline__ void insert3_fast(float c, int ci,
                                             float &v0, int &i0,
                                             float &v1, int &i1,
                                             float &v2, int &i2) {
  const bool b2 = c > v2;
  const bool b1 = c > v1;
  const bool b0 = c > v0;
  v2 = b1 ? v1 : (b2 ? c : v2);  i2 = b1 ? i1 : (b2 ? ci : i2);
  v1 = b0 ? v0 : (b1 ? c : v1);  i1 = b0 ? i0 : (b1 ? ci : i1);
  v0 = b0 ? c  : v0;             i0 = b0 ? ci : i0;
}

__global__ __launch_bounds__(BLOCK, 4)
void detect_peaks_kernel(const float* __restrict__ x,
                         float* __restrict__ out,
                         int rows) {
  __shared__ float rv[12];
  __shared__ int   ri[12];

  const int row  = blockIdx.x;
  const int t    = threadIdx.x;
  const int lane = t & 63;
  const int wave = t >> 6;
  const float* __restrict__ xr = x + (size_t)row * PW;

  const int waveQ = wave * (J * 64);          // first quad of this wave's span
  const int spanL = waveQ * 4;                // first element of span
  const int spanR = spanL + J * 64 * 4;       // one past last element

  // clamped edge addresses (wave-uniform; -inf substituted at row boundaries below)
  const float* pL = xr + (spanL > 0 ? spanL - 1 : 0);
  const float* pR = xr + (spanR < PW ? spanR : PW - 1);

  const float* a0 = xr + (size_t)(waveQ + 0 * 64 + lane) * 4;
  const float* a1 = xr + (size_t)(waveQ + 1 * 64 + lane) * 4;
  const float* a2 = xr + (size_t)(waveQ + 2 * 64 + lane) * 4;
  const float* a3 = xr + (size_t)(waveQ + 3 * 64 + lane) * 4;
  const float* a4 = xr + (size_t)(waveQ + 4 * 64 + lane) * 4;
  const float* a5 = xr + (size_t)(waveQ + 5 * 64 + lane) * 4;
  const float* a6 = xr + (size_t)(waveQ + 6 * 64 + lane) * 4;
  const float* a7 = xr + (size_t)(waveQ + 7 * 64 + lane) * 4;

  // ---- ONE asm block: 10 loads issued back-to-back, drained in-block. Sound: outputs
  // only live after the waitcnt; earlyclobber prevents dest/address aliasing. ----
  float4 q0, q1, q2, q3, q4, q5, q6, q7;
  float eLv, eRv;
  asm volatile(
      "global_load_dwordx4 %0, %10, off\n\t"
      "global_load_dwordx4 %1, %11, off\n\t"
      "global_load_dwordx4 %2, %12, off\n\t"
      "global_load_dwordx4 %3, %13, off\n\t"
      "global_load_dwordx4 %4, %14, off\n\t"
      "global_load_dwordx4 %5, %15, off\n\t"
      "global_load_dwordx4 %6, %16, off\n\t"
      "global_load_dwordx4 %7, %17, off\n\t"
      "global_load_dword   %8, %18, off\n\t"
      "global_load_dword   %9, %19, off\n\t"
      "s_waitcnt vmcnt(0)"
      : "=&v"(q0), "=&v"(q1), "=&v"(q2), "=&v"(q3),
        "=&v"(q4), "=&v"(q5), "=&v"(q6), "=&v"(q7),
        "=&v"(eLv), "=&v"(eRv)
      : "v"(a0), "v"(a1), "v"(a2), "v"(a3),
        "v"(a4), "v"(a5), "v"(a6), "v"(a7),
        "v"(pL), "v"(pR));

  const float eL = (wave == 0)      ? -INFINITY : eLv;
  const float eR = (wave == NW - 1) ? -INFINITY : eRv;

  float4 q[J] = {q0, q1, q2, q3, q4, q5, q6, q7};

  float v0 = -INFINITY, v1 = -INFINITY, v2 = -INFINITY;
  int   i0 = INT_MAX,   i1 = INT_MAX,   i2 = INT_MAX;

#pragma unroll
  for (int j = 0; j < J; ++j) {
    const int p = (waveQ + j * 64 + lane) * 4;
    const float4 v = q[j];

    // neighbors via shfl; wave-span edges from the uniform edge loads
    const float lu = __shfl_up(v.w, 1);
    const float l0 = (j > 0) ? __shfl(q[j - 1].w, 63) : eL;
    const float left = (lane == 0) ? l0 : lu;
    const float rd = __shfl_down(v.x, 1);
    const float r0 = (j < J - 1) ? __shfl(q[j + 1].x, 0) : eR;
    const float right = (lane == 63) ? r0 : rd;

    // sliding 3-max over the 4 positions
    const float p01 = fmaxf(v.x, v.y);
    const float p12 = fmaxf(v.y, v.z);
    const float p23 = fmaxf(v.z, v.w);
    const float m0 = fmaxf(left, p01);
    const float m1 = fmaxf(p01, v.z);
    const float m2 = fmaxf(p12, v.w);
    const float m3 = fmaxf(p23, right);

    // NMS score: x where local max else 0
    const float s0 = (v.x == m0) ? v.x : 0.0f;
    const float s1 = (v.y == m1) ? v.y : 0.0f;
    const float s2 = (v.z == m2) ? v.z : 0.0f;
    const float s3 = (v.w == m3) ? v.w : 0.0f;

    // quad top-2 (left arg of >= always lower index => tie->lower-index preserved);
    // a window of 4 contiguous lags holds at most 2 local maxima.
    const bool  a01 = s0 >= s1;
    const float hiA = a01 ? s0 : s1;   const int hiAi = a01 ? p     : p + 1;
    const float loA = a01 ? s1 : s0;   const int loAi = a01 ? p + 1 : p;
    const bool  a23 = s2 >= s3;
    const float hiB = a23 ? s2 : s3;   const int hiBi = a23 ? p + 2 : p + 3;
    const float loB = a23 ? s3 : s2;   const int loBi = a23 ? p + 3 : p + 2;

    const bool  ab  = hiA >= hiB;
    const float c1  = ab ? hiA : hiB;  const int c1i = ab ? hiAi : hiBi;
    const bool  sb  = ab ? (loA >= hiB) : (hiA >= loB);
    const float c2  = ab ? (sb ? loA : hiB) : (sb ? hiA : loB);
    const int   c2i = ab ? (sb ? loAi : hiBi) : (sb ? hiAi : loBi);

    insert3_fast(c1, c1i, v0, i0, v1, i1, v2, i2);
    insert3_fast(c2, c2i, v0, i0, v1, i1, v2, i2);
  }

  // ---- wave-level tree merge (64 lanes) ----
#pragma unroll
  for (int off = 32; off > 0; off >>= 1) {
    float ov0 = __shfl_down(v0, off);
    int   oi0 = __shfl_down(i0, off);
    float ov1 = __shfl_down(v1, off);
    int   oi1 = __shfl_down(i1, off);
    float ov2 = __shfl_down(v2, off);
    int   oi2 = __shfl_down(i2, off);
    if (lane + off < 64) {
      insert3_full(ov0, oi0, v0, i0, v1, i1, v2, i2);
      insert3_full(ov1, oi1, v0, i0, v1, i1, v2, i2);
      insert3_full(ov2, oi2, v0, i0, v1, i1, v2, i2);
    }
  }

  if (lane == 0) {
    rv[wave * 3 + 0] = v0; ri[wave * 3 + 0] = i0;
    rv[wave * 3 + 1] = v1; ri[wave * 3 + 1] = i1;
    rv[wave * 3 + 2] = v2; ri[wave * 3 + 2] = i2;
  }
  __syncthreads();

  if (t == 0) {
#pragma unroll
    for (int w = 1; w < NW; ++w) {
      insert3_full(rv[w * 3 + 0], ri[w * 3 + 0], v0, i0, v1, i1, v2, i2);
      insert3_full(rv[w * 3 + 1], ri[w * 3 + 1], v0, i0, v1, i1, v2, i2);
      insert3_full(rv[w * 3 + 2], ri[w * 3 + 2], v0, i0, v1, i1, v2, i2);
    }

    float* __restrict__ nb = out;                      // neighbor_score
    float* __restrict__ ts = out + (size_t)rows * 3;   // topk_scores
    float* __restrict__ ti = out + (size_t)rows * 6;   // topk_index (as float)

    const int top = i0;
#pragma unroll
    for (int k = 0; k < 3; ++k) {
      int idx = top - 1 + k;
      idx = idx < 0 ? 0 : (idx > PW - 1 ? PW - 1 : idx);
      nb[row * 3 + k] = xr[idx];                       // L2-warm gather
    }
    ts[row * 3 + 0] = v0;
    ts[row * 3 + 1] = v1;
    ts[row * 3 + 2] = v2;
    ti[row * 3 + 0] = (float)(i0 - PNLAG);
    ti[row * 3 + 1] = (float)(i1 - PNLAG);
    ti[row * 3 + 2] = (float)(i2 - PNLAG);
  }
}

extern "C" void kernel_launch(void* const* d_in, const int* in_sizes, int n_in,
                              void* d_out, int out_size, void* d_ws, size_t ws_size,
                              hipStream_t stream) {
  const float* x = (const float*)d_in[0];
  float* out = (float*)d_out;
  const int rows = in_sizes[0] / PW;   // 4096
  detect_peaks_kernel<<<rows, BLOCK, 0, stream>>>(x, out, rows);
}